// Round 11
// baseline (436.244 us; speedup 1.0000x reference)
//
#include <hip/hip_runtime.h>

#define D 128

__device__ __forceinline__ int idx_at(const int* __restrict__ w, int n, bool is64) {
    return is64 ? w[2 * n] : w[n];
}

// ---------------- bounds via per-thread binary search (proven, round 6) -----
__global__ __launch_bounds__(256) void bounds_kernel(
    const int* __restrict__ w, int N, int S, int* __restrict__ segstart) {
    const int lane = threadIdx.x & 63;
    const int quarter = N >> 2;
    const int n0 = quarter + (int)(((long long)(quarter - 64) * lane) / 64);
    unsigned v = ((const unsigned*)w)[2 * n0 + 1];
#pragma unroll
    for (int m = 32; m; m >>= 1) v |= __shfl_xor(v, m, 64);
    const bool is64 = (v == 0u);
    const int s = blockIdx.x * blockDim.x + threadIdx.x;
    if (s > S) return;
    if (s == S) { segstart[S] = N; return; }
    int lo = 0, hi = N;
    while (lo < hi) {
        const int mid = (lo + hi) >> 1;
        if (idx_at(w, mid, is64) < s) lo = mid + 1; else hi = mid;
    }
    segstart[s] = lo;
}

// ---------------- gate pass: g[n] = exp(x[n]@Wg + bg), row per THREAD -------
// No cross-lane ops: each thread serially dots its own 512-B row (32 float4
// loads, unroll 8 -> 8 independent lines in flight; consecutive same-line
// accesses hit L1). Wg broadcast from LDS (same addr across lanes). Writes
// are 256 B/wave contiguous. This isolates "stream x + rowwise reduce" from
// the segmented accumulate.
__global__ __launch_bounds__(256) void gate_kernel(
    const float* __restrict__ x, const float* __restrict__ Wg,
    const float* __restrict__ bg, float* __restrict__ g, int N) {
    __shared__ float wg_s[D];
    const int tid = threadIdx.x;
    if (tid < D) wg_s[tid] = Wg[tid];
    __syncthreads();
    const int n = blockIdx.x * blockDim.x + tid;
    if (n >= N) return;
    const float4* __restrict__ xr = (const float4*)(x + (size_t)n * D);
    const float4* __restrict__ wg4 = (const float4*)wg_s;
    float4 acc0 = {0.f, 0.f, 0.f, 0.f};
    float4 acc1 = {0.f, 0.f, 0.f, 0.f};
#pragma unroll 4
    for (int k = 0; k < 32; k += 2) {
        const float4 a0 = xr[k];
        const float4 a1 = xr[k + 1];
        const float4 w0 = wg4[k];
        const float4 w1 = wg4[k + 1];
        acc0.x += a0.x * w0.x; acc0.y += a0.y * w0.y;
        acc0.z += a0.z * w0.z; acc0.w += a0.w * w0.w;
        acc1.x += a1.x * w1.x; acc1.y += a1.y * w1.y;
        acc1.z += a1.z * w1.z; acc1.w += a1.w * w1.w;
    }
    const float dot = (acc0.x + acc0.y) + (acc0.z + acc0.w) +
                      (acc1.x + acc1.y) + (acc1.z + acc1.w);
    g[n] = __expf(dot + bg[0]);
}

// ---------------- accum pass: wx[s] = sum g*x / sum g (wave per segment) ----
// Same proven coalesced pattern (lanes 0-31 row r, 32-63 row r+1, float4),
// but NO butterfly and NO exp in the stream: gates are broadcast scalar
// loads. Pure load->FMA stream; one cross-half merge at the end.
__global__ __launch_bounds__(256) void accum_kernel(
    const float* __restrict__ x, const float* __restrict__ g,
    const int* __restrict__ segstart, float* __restrict__ wx,
    float* __restrict__ segf, int S) {
    const int wid = threadIdx.x >> 6;
    const int lane = threadIdx.x & 63;
    const int s = blockIdx.x * 4 + wid;
    if (s >= S) return;
    const int start = segstart[s];
    const int end = segstart[s + 1];
    const int half = lane >> 5;
    const int c4 = (lane & 31) * 4;
    float4 acc = {0.f, 0.f, 0.f, 0.f};
    float us = 0.f;
    int r = start;
    for (; r + 8 <= end; r += 8) {
        const float4 a0 = *(const float4*)&x[(size_t)(r + 0 + half) * D + c4];
        const float4 a1 = *(const float4*)&x[(size_t)(r + 2 + half) * D + c4];
        const float4 a2 = *(const float4*)&x[(size_t)(r + 4 + half) * D + c4];
        const float4 a3 = *(const float4*)&x[(size_t)(r + 6 + half) * D + c4];
        const float e0 = g[r + 0 + half];
        const float e1 = g[r + 2 + half];
        const float e2 = g[r + 4 + half];
        const float e3 = g[r + 6 + half];
        us += (e0 + e1) + (e2 + e3);
        acc.x += e0 * a0.x + e1 * a1.x + e2 * a2.x + e3 * a3.x;
        acc.y += e0 * a0.y + e1 * a1.y + e2 * a2.y + e3 * a3.y;
        acc.z += e0 * a0.z + e1 * a1.z + e2 * a2.z + e3 * a3.z;
        acc.w += e0 * a0.w + e1 * a1.w + e2 * a2.w + e3 * a3.w;
    }
    for (; r < end; r += 2) {
        int row = r + half;
        if (row > end - 1) row = end - 1;   // clamp (no OOB); e zeroed below
        const float4 a = *(const float4*)&x[(size_t)row * D + c4];
        float e = g[row];
        if (half && r + 1 >= end) e = 0.f;  // odd tail: upper half contributes 0
        us += e;
        acc.x += e * a.x;
        acc.y += e * a.y;
        acc.z += e * a.z;
        acc.w += e * a.w;
    }
    // merge the two halves (same columns, disjoint row subsets)
    us += __shfl_xor(us, 32, 64);
    acc.x += __shfl_xor(acc.x, 32, 64);
    acc.y += __shfl_xor(acc.y, 32, 64);
    acc.z += __shfl_xor(acc.z, 32, 64);
    acc.w += __shfl_xor(acc.w, 32, 64);
    const float inv = 1.f / (us + 1e-10f);  // empty segment: 0
    if (half == 0) {
        float4 o;
        o.x = acc.x * inv;
        o.y = acc.y * inv;
        o.z = acc.z * inv;
        o.w = acc.w * inv;
        *(float4*)&wx[(size_t)s * D + c4] = o;
    }
    if (lane == 0) segf[s] = us * inv;  // sum of gates (~1 nonempty, 0 empty)
}

// ---------------- out = wx @ Wm + segf * bm (in-place on d_out, proven) -----
__global__ __launch_bounds__(64) void gemm_kernel(
    float* __restrict__ out, const float* __restrict__ Wm,
    const float* __restrict__ bm, const float* __restrict__ segf) {
    __shared__ float tile[16 * 128];
    const int s0 = blockIdx.x * 16;
    const int tid = threadIdx.x;
    for (int t = tid; t < 16 * 128; t += 64) tile[t] = out[(size_t)s0 * 128 + t];
    __syncthreads();
    float2 acc[16];
#pragma unroll
    for (int r = 0; r < 16; ++r) { acc[r].x = 0.f; acc[r].y = 0.f; }
    for (int k = 0; k < 128; ++k) {
        const float2 wm = *(const float2*)&Wm[k * 128 + 2 * tid];
#pragma unroll
        for (int r = 0; r < 16; ++r) {
            const float wv = tile[r * 128 + k];  // LDS broadcast: conflict-free
            acc[r].x += wv * wm.x;
            acc[r].y += wv * wm.y;
        }
    }
    const float2 bmv = *(const float2*)&bm[2 * tid];
#pragma unroll
    for (int r = 0; r < 16; ++r) {
        const int s = s0 + r;
        const float f = segf[s];
        float2 o;
        o.x = acc[r].x + f * bmv.x;
        o.y = acc[r].y + f * bmv.y;
        *(float2*)&out[(size_t)s * 128 + 2 * tid] = o;
    }
}

extern "C" void kernel_launch(void* const* d_in, const int* in_sizes, int n_in,
                              void* d_out, int out_size, void* d_ws, size_t ws_size,
                              hipStream_t stream) {
    const float* x  = (const float*)d_in[0];
    const int*   w  = (const int*)d_in[1];   // index: int32 or int64, auto-detected
    const float* Wg = (const float*)d_in[2];
    const float* bg = (const float*)d_in[3];
    const float* Wm = (const float*)d_in[4];
    const float* bm = (const float*)d_in[5];
    float* out = (float*)d_out;

    const int N = in_sizes[1];
    const int S = out_size / D;  // 16384

    char* wsb = (char*)d_ws;
    int* segstart = (int*)wsb;                       // S+1 ints
    float* segf = (float*)(segstart + S + 1);        // S floats
    float* g = (float*)(wsb + ((4 * (2 * S + 1) + 255) & ~255));  // N floats

    bounds_kernel<<<(S + 1 + 255) / 256, 256, 0, stream>>>(w, N, S, segstart);
    gate_kernel<<<(N + 255) / 256, 256, 0, stream>>>(x, Wg, bg, g, N);
    accum_kernel<<<(S + 3) / 4, 256, 0, stream>>>(x, g, segstart, out, segf, S);
    gemm_kernel<<<S / 16, 64, 0, stream>>>(out, Wm, bm, segf);
}